// Round 5
// baseline (15.131 us; speedup 1.0000x reference)
//
#include <hip/hip_runtime.h>
#include <hip/hip_bf16.h>

// out[b,k] = relu( sum_d (obs*mask)[b,d]*G[d,k] + s1[b]*W[10,k] + s0[b]*bw[k] )
// G[d,k] = sum_f F[d,f]*W[f,k];  s0[b]=sum_d mask;  s1[b]=sum_d mask*bvec[d]
// B=4096, D=512, K=64.
//
// SINGLE fused kernel (no prep launch): each block computes G itself via
// 32 mfma_16x16x32_bf16 per wave (f-dim 10 padded to K=32 with zeros),
// writing main-GEMM B-fragments straight into LDS in fragment-major order
// (main B-reads = 64 consecutive 16B slots -> conflict-free). obs/mask loads
// are issued BEFORE the G phase so G-compute hides under HBM latency.
// 512 blocks x 256 thr (4 waves), 8 rows/block, LDS 72KB -> 2 blocks/CU.

#define D_DIM 512
#define K_DIM 64
#define B_DIM 4096

typedef __attribute__((ext_vector_type(4))) float f32x4;
typedef __attribute__((ext_vector_type(8))) short bf16x8;

__device__ __forceinline__ unsigned short f2bf(float f) {
    unsigned u = __builtin_bit_cast(unsigned, f);
    u += 0x7fffu + ((u >> 16) & 1u);          // RNE
    return (unsigned short)(u >> 16);
}
__device__ __forceinline__ unsigned pack2(float a, float b) {
    return (unsigned)f2bf(a) | ((unsigned)f2bf(b) << 16);
}

__global__ __launch_bounds__(256, 2)
void fused_kernel(const float* __restrict__ obs,
                  const float* __restrict__ mask,
                  const float* __restrict__ bvec,
                  const float* __restrict__ F,
                  const float* __restrict__ W,
                  const float* __restrict__ bw,
                  float* __restrict__ out) {
    // GF: main-GEMM B-frags, slot (wv*16+tp)*64+lane holds 8 bf16
    //     = G[tp*32+(lane>>4)*8+j][wv*16+(lane&15)], j=0..7.
    __shared__ __align__(16) unsigned short GF[4096 * 8];   // 64 KB
    // XF: main-GEMM A-frags, slot r*64+((tp*4+g)^r) holds 8 bf16
    //     = X[r][tp*32+g*8+j].
    __shared__ __align__(16) unsigned short XF[512 * 8];    // 8 KB
    __shared__ float s0s[8], s1s[8];

    const int tid  = threadIdx.x;
    const int lane = tid & 63;
    const int w    = tid >> 6;          // wave 0..3
    const int ln   = lane & 15;
    const int g    = lane >> 4;         // 0..3
    const int rowbase = blockIdx.x * 8;

    // ---- 1. issue staging loads (fire-and-forget; used in phase 3) ----
    const int r = tid >> 5;             // row 0..7 (32 threads/row)
    const int c = tid & 31;
    const float* orow = obs  + (size_t)(rowbase + r) * D_DIM;
    const float* mrow = mask + (size_t)(rowbase + r) * D_DIM;
    f32x4 o[4], m[4], bv[4];
#pragma unroll
    for (int j = 0; j < 4; ++j) {
        int d = c * 4 + 128 * j;
        o[j]  = *reinterpret_cast<const f32x4*>(orow + d);
        m[j]  = *reinterpret_cast<const f32x4*>(mrow + d);
        bv[j] = *reinterpret_cast<const f32x4*>(bvec + d);
    }

    // ---- 2. G phase: compute G = F@W[0:10] via MFMA into GF (LDS) ----
    {
        // B-frags from W: wf[nt][j] = bf16(W[k][nt*16+ln]), k=g*8+j (0 if k>=10)
        bf16x8 wf[4];
#pragma unroll
        for (int nt = 0; nt < 4; ++nt) {
#pragma unroll
            for (int j = 0; j < 8; ++j) {
                int k = g * 8 + j;
                wf[nt][j] = (k < 10)
                    ? (short)f2bf(W[k * K_DIM + nt * 16 + ln]) : (short)0;
            }
        }
        // 8 d-tiles of 16 per wave: dt = w*8+i covers d rows dt*16..dt*16+15
#pragma unroll
        for (int i = 0; i < 8; ++i) {
            const int dt = w * 8 + i;
            const int Frow = dt * 16 + ln;
            const float* Fr = F + (size_t)Frow * 10;
            float fa[8] = {0.f, 0.f, 0.f, 0.f, 0.f, 0.f, 0.f, 0.f};
            if (g == 0) {
                float2 t0 = *reinterpret_cast<const float2*>(Fr + 0);
                float2 t1 = *reinterpret_cast<const float2*>(Fr + 2);
                float2 t2 = *reinterpret_cast<const float2*>(Fr + 4);
                float2 t3 = *reinterpret_cast<const float2*>(Fr + 6);
                fa[0] = t0.x; fa[1] = t0.y; fa[2] = t1.x; fa[3] = t1.y;
                fa[4] = t2.x; fa[5] = t2.y; fa[6] = t3.x; fa[7] = t3.y;
            } else if (g == 1) {
                float2 t = *reinterpret_cast<const float2*>(Fr + 8);
                fa[0] = t.x; fa[1] = t.y;           // k=8,9; k>=10 zero
            }
            bf16x8 af;
#pragma unroll
            for (int j = 0; j < 8; ++j) af[j] = (short)f2bf(fa[j]);

#pragma unroll
            for (int nt = 0; nt < 4; ++nt) {
                f32x4 gacc = {0.f, 0.f, 0.f, 0.f};
                gacc = __builtin_amdgcn_mfma_f32_16x16x32_bf16(af, wf[nt], gacc, 0, 0, 0);
                // lane holds G[dt*16 + g*4 + rr][nt*16 + ln], rr=0..3
                // -> fragment slot, j-run = (g&1)*4 + rr (8B write)
                int slot = (nt * 16 + (dt >> 1)) * 64 + ((dt & 1) * 2 + (g >> 1)) * 16 + ln;
                uint2 val;
                val.x = pack2(gacc[0], gacc[1]);
                val.y = pack2(gacc[2], gacc[3]);
                *reinterpret_cast<uint2*>(
                    reinterpret_cast<char*>(GF) + slot * 16 + (g & 1) * 8) = val;
            }
        }
    }

    // ---- 3. X staging into XF (A-frag layout) + s0/s1 reductions ----
    {
        float p0 = 0.f, p1 = 0.f;
#pragma unroll
        for (int j = 0; j < 4; ++j) {
            uint2 xv;
            xv.x = pack2(o[j].x * m[j].x, o[j].y * m[j].y);
            xv.y = pack2(o[j].z * m[j].z, o[j].w * m[j].w);
            // d = c*4 + 128j -> tp=(c>>3)+4j, gch=(c>>1)&3, half=c&1
            int tp   = (c >> 3) + 4 * j;
            int gch  = (c >> 1) & 3;
            int slot = r * 64 + ((tp * 4 + gch) ^ r);
            *reinterpret_cast<uint2*>(
                reinterpret_cast<char*>(XF) + slot * 16 + (c & 1) * 8) = xv;
            p0 += (m[j].x + m[j].y) + (m[j].z + m[j].w);
            p1 = fmaf(m[j].x, bv[j].x, p1);
            p1 = fmaf(m[j].y, bv[j].y, p1);
            p1 = fmaf(m[j].z, bv[j].z, p1);
            p1 = fmaf(m[j].w, bv[j].w, p1);
        }
#pragma unroll
        for (int s = 1; s <= 16; s <<= 1) {    // reduce across 32-thread row-group
            p0 += __shfl_xor(p0, s, 64);
            p1 += __shfl_xor(p1, s, 64);
        }
        if (c == 0) { s0s[r] = p0; s1s[r] = p1; }
    }
    __syncthreads();

    // ---- 4. main MFMA: 16 steps of K=32 over d=512 ----
    f32x4 acc = {0.f, 0.f, 0.f, 0.f};
    {
        const int arow = lane & 7;             // rows 8..15 duplicate 0..7
        const char* xb = reinterpret_cast<const char*>(XF);
        const char* gb = reinterpret_cast<const char*>(GF);
#pragma unroll
        for (int tp = 0; tp < 16; ++tp) {
            bf16x8 a = *reinterpret_cast<const bf16x8*>(
                xb + (arow * 64 + ((tp * 4 + g) ^ arow)) * 16);
            bf16x8 b = *reinterpret_cast<const bf16x8*>(
                gb + ((w * 16 + tp) * 64 + lane) * 16);
            acc = __builtin_amdgcn_mfma_f32_16x16x32_bf16(a, b, acc, 0, 0, 0);
        }
    }

    // ---- 5. epilogue: rows 0..7 live in lanes 0..31 ----
    const int kk = w * 16 + ln;
    if (lane < 32) {
        const float w10 = W[10 * K_DIM + kk];
        const float bwv = bw[kk];
#pragma unroll
        for (int rr = 0; rr < 4; ++rr) {
            const int rowl = g * 4 + rr;       // g in {0,1}: C/D row=(lane>>4)*4+reg
            float tot = acc[rr];
            tot = fmaf(s1s[rowl], w10, tot);
            tot = fmaf(s0s[rowl], bwv, tot);
            out[(size_t)(rowbase + rowl) * K_DIM + kk] = fmaxf(tot, 0.f);
        }
    }
}

extern "C" void kernel_launch(void* const* d_in, const int* in_sizes, int n_in,
                              void* d_out, int out_size, void* d_ws, size_t ws_size,
                              hipStream_t stream) {
    const float* obs  = (const float*)d_in[0];  // [4096, 512]
    const float* mask = (const float*)d_in[1];  // [4096, 512]
    const float* F    = (const float*)d_in[2];  // [1, 512, 10]
    const float* bvec = (const float*)d_in[3];  // [1, 512, 1]
    const float* W    = (const float*)d_in[4];  // [11, 64]
    const float* bw   = (const float*)d_in[5];  // [64]
    float* out = (float*)d_out;                 // [4096, 64]

    fused_kernel<<<B_DIM / 8, 256, 0, stream>>>(obs, mask, bvec, F, W, bw, out);
}

// Round 6
// 14.827 us; speedup vs baseline: 1.0204x; 1.0204x over previous
//
#include <hip/hip_runtime.h>
#include <hip/hip_bf16.h>

// out[b,k] = relu( sum_d (obs*mask)[b,d]*G[d,k] + s1[b]*W[10,k] + s0[b]*bw[k] )
// G[d,k] = sum_f F[d,f]*W[f,k];  s0[b]=sum_d mask;  s1[b]=sum_d mask*bvec[d]
// B=4096, D=512, K=64.
//
// Persistent fused kernel: 256 blocks (1/CU) x 256 thr (4 waves), 16 rows each
// in 2 pipelined batches of 8. G = F@W[0:10] computed ONCE per block via MFMA
// (f padded 10->32), fragments redistributed through 64 KB LDS (layout
// verified in round 5). Batch-1 obs/mask loads are register-staged before
// batch-0's MFMA phase. B-fragments read from LDS (fragment-major,
// conflict-free) each step -> low VGPR, no spills.

#define D_DIM 512
#define K_DIM 64
#define B_DIM 4096

typedef __attribute__((ext_vector_type(4))) float f32x4;
typedef __attribute__((ext_vector_type(8))) short bf16x8;

__device__ __forceinline__ unsigned short f2bf(float f) {
    unsigned u = __builtin_bit_cast(unsigned, f);
    u += 0x7fffu + ((u >> 16) & 1u);          // RNE
    return (unsigned short)(u >> 16);
}
__device__ __forceinline__ unsigned pack2(float a, float b) {
    return (unsigned)f2bf(a) | ((unsigned)f2bf(b) << 16);
}

__global__ __launch_bounds__(256, 1)
void fused_kernel(const float* __restrict__ obs,
                  const float* __restrict__ mask,
                  const float* __restrict__ bvec,
                  const float* __restrict__ F,
                  const float* __restrict__ W,
                  const float* __restrict__ bw,
                  float* __restrict__ out) {
    // GF: main-GEMM B-frags, slot (wv*16+tp)*64+lane holds 8 bf16
    //     = G[tp*32+(lane>>4)*8+j][wv*16+(lane&15)], j=0..7.
    __shared__ __align__(16) unsigned short GF[4096 * 8];     // 64 KB
    // XF[b]: A-frags for batch b, slot r*64+((tp*4+g)^r) holds 8 bf16
    //        = X[r][tp*32+g*8+j].
    __shared__ __align__(16) unsigned short XF[2][512 * 8];   // 16 KB
    __shared__ float s0s[2][8], s1s[2][8];

    const int tid  = threadIdx.x;
    const int lane = tid & 63;
    const int w    = tid >> 6;          // wave 0..3
    const int ln   = lane & 15;
    const int g    = lane >> 4;         // 0..3
    const int rowbase = blockIdx.x * 16;

    const int r = tid >> 5;             // row 0..7 (32 threads/row)
    const int c = tid & 31;

    // ---- bvec columns (identical for both batches) ----
    f32x4 bv[4];
#pragma unroll
    for (int j = 0; j < 4; ++j)
        bv[j] = *reinterpret_cast<const f32x4*>(bvec + c * 4 + 128 * j);

    // ---- issue batch-0 obs/mask loads (latency hides under G phase) ----
    f32x4 o[4], m[4];
    auto issue_loads = [&](int b) {
        const float* orow = obs  + (size_t)(rowbase + b * 8 + r) * D_DIM;
        const float* mrow = mask + (size_t)(rowbase + b * 8 + r) * D_DIM;
#pragma unroll
        for (int j = 0; j < 4; ++j) {
            int d = c * 4 + 128 * j;
            o[j] = *reinterpret_cast<const f32x4*>(orow + d);
            m[j] = *reinterpret_cast<const f32x4*>(mrow + d);
        }
    };
    issue_loads(0);

    // ---- G phase: G = F@W[0:10] via MFMA into GF (verified round-5) ----
    {
        bf16x8 wf[4];
#pragma unroll
        for (int nt = 0; nt < 4; ++nt) {
#pragma unroll
            for (int j = 0; j < 8; ++j) {
                int k = g * 8 + j;
                wf[nt][j] = (k < 10)
                    ? (short)f2bf(W[k * K_DIM + nt * 16 + ln]) : (short)0;
            }
        }
#pragma unroll
        for (int i = 0; i < 8; ++i) {
            const int dt = w * 8 + i;
            const int Frow = dt * 16 + ln;
            const float* Fr = F + (size_t)Frow * 10;
            float fa[8] = {0.f, 0.f, 0.f, 0.f, 0.f, 0.f, 0.f, 0.f};
            if (g == 0) {
                float2 t0 = *reinterpret_cast<const float2*>(Fr + 0);
                float2 t1 = *reinterpret_cast<const float2*>(Fr + 2);
                float2 t2 = *reinterpret_cast<const float2*>(Fr + 4);
                float2 t3 = *reinterpret_cast<const float2*>(Fr + 6);
                fa[0] = t0.x; fa[1] = t0.y; fa[2] = t1.x; fa[3] = t1.y;
                fa[4] = t2.x; fa[5] = t2.y; fa[6] = t3.x; fa[7] = t3.y;
            } else if (g == 1) {
                float2 t = *reinterpret_cast<const float2*>(Fr + 8);
                fa[0] = t.x; fa[1] = t.y;           // k=8,9; k>=10 zero
            }
            bf16x8 af;
#pragma unroll
            for (int j = 0; j < 8; ++j) af[j] = (short)f2bf(fa[j]);

#pragma unroll
            for (int nt = 0; nt < 4; ++nt) {
                f32x4 gacc = {0.f, 0.f, 0.f, 0.f};
                gacc = __builtin_amdgcn_mfma_f32_16x16x32_bf16(af, wf[nt], gacc, 0, 0, 0);
                int slot = (nt * 16 + (dt >> 1)) * 64 + ((dt & 1) * 2 + (g >> 1)) * 16 + ln;
                uint2 val;
                val.x = pack2(gacc[0], gacc[1]);
                val.y = pack2(gacc[2], gacc[3]);
                *reinterpret_cast<uint2*>(
                    reinterpret_cast<char*>(GF) + slot * 16 + (g & 1) * 8) = val;
            }
        }
    }

    // ---- epilogue constants ----
    const int kk = w * 16 + ln;
    const float w10 = W[10 * K_DIM + kk];
    const float bwv = bw[kk];

    // ---- stage batch b: X -> XF[b] (A-frag layout) + s0/s1 ----
    auto stage = [&](int b) {
        float p0 = 0.f, p1 = 0.f;
        char* xb = reinterpret_cast<char*>(XF[b]);
#pragma unroll
        for (int j = 0; j < 4; ++j) {
            uint2 xv;
            xv.x = pack2(o[j].x * m[j].x, o[j].y * m[j].y);
            xv.y = pack2(o[j].z * m[j].z, o[j].w * m[j].w);
            int tp   = (c >> 3) + 4 * j;
            int gch  = (c >> 1) & 3;
            int slot = r * 64 + ((tp * 4 + gch) ^ r);
            *reinterpret_cast<uint2*>(xb + slot * 16 + (c & 1) * 8) = xv;
            p0 += (m[j].x + m[j].y) + (m[j].z + m[j].w);
            p1 = fmaf(m[j].x, bv[j].x, p1);
            p1 = fmaf(m[j].y, bv[j].y, p1);
            p1 = fmaf(m[j].z, bv[j].z, p1);
            p1 = fmaf(m[j].w, bv[j].w, p1);
        }
#pragma unroll
        for (int s = 1; s <= 16; s <<= 1) {    // reduce across 32-thread row-group
            p0 += __shfl_xor(p0, s, 64);
            p1 += __shfl_xor(p1, s, 64);
        }
        if (c == 0) { s0s[b][r] = p0; s1s[b][r] = p1; }
    };

    f32x4 acc;
    auto mfma_batch = [&](int b) {
        acc[0] = acc[1] = acc[2] = acc[3] = 0.f;
        const int arow = lane & 7;             // rows 8..15 duplicate 0..7
        const char* xb = reinterpret_cast<const char*>(XF[b]);
        const char* gb = reinterpret_cast<const char*>(GF);
#pragma unroll
        for (int tp = 0; tp < 16; ++tp) {
            bf16x8 a = *reinterpret_cast<const bf16x8*>(
                xb + (arow * 64 + ((tp * 4 + g) ^ arow)) * 16);
            bf16x8 bfr = *reinterpret_cast<const bf16x8*>(
                gb + ((w * 16 + tp) * 64 + lane) * 16);
            acc = __builtin_amdgcn_mfma_f32_16x16x32_bf16(a, bfr, acc, 0, 0, 0);
        }
    };

    auto epilogue = [&](int b) {
        if (lane < 32) {                       // g in {0,1}
#pragma unroll
            for (int rr = 0; rr < 4; ++rr) {
                const int rowl = g * 4 + rr;   // C/D: row=(lane>>4)*4+reg
                float tot = acc[rr];
                tot = fmaf(s1s[b][rowl], w10, tot);
                tot = fmaf(s0s[b][rowl], bwv, tot);
                out[(size_t)(rowbase + b * 8 + rowl) * K_DIM + kk] = fmaxf(tot, 0.f);
            }
        }
    };

    // ---- pipeline: stage0 | bar | issue1, mfma0, epi0, stage1 | bar | mfma1, epi1
    stage(0);
    __syncthreads();                 // GF + XF[0] + s0s[0] ready

    issue_loads(1);                  // batch-1 HBM loads fly under mfma(0)
    mfma_batch(0);
    epilogue(0);
    stage(1);                        // lands batch-1 into XF[1]
    __syncthreads();                 // XF[1] + s0s[1] ready

    mfma_batch(1);
    epilogue(1);
}

extern "C" void kernel_launch(void* const* d_in, const int* in_sizes, int n_in,
                              void* d_out, int out_size, void* d_ws, size_t ws_size,
                              hipStream_t stream) {
    const float* obs  = (const float*)d_in[0];  // [4096, 512]
    const float* mask = (const float*)d_in[1];  // [4096, 512]
    const float* F    = (const float*)d_in[2];  // [1, 512, 10]
    const float* bvec = (const float*)d_in[3];  // [1, 512, 1]
    const float* W    = (const float*)d_in[4];  // [11, 64]
    const float* bw   = (const float*)d_in[5];  // [64]
    float* out = (float*)d_out;                 // [4096, 64]

    fused_kernel<<<B_DIM / 16, 256, 0, stream>>>(obs, mask, bvec, F, W, bw, out);
}

// Round 7
// 13.348 us; speedup vs baseline: 1.1335x; 1.1108x over previous
//
#include <hip/hip_runtime.h>
#include <hip/hip_bf16.h>

// out[b,k] = relu( sum_d (obs*mask)[b,d]*G[d,k] + s1[b]*W[10,k] + s0[b]*bw[k] )
// G[d,k] = sum_f F[d,f]*W[f,k];  s0[b]=sum_d mask;  s1[b]=sum_d mask*bvec[d]
// B=4096, D=512, K=64.  GEMM in bf16 MFMA (threshold 1.64 >> bf16 err ~0.5).
//
// Champion structure (round 3, 12.97 us) + load-order micro-opt:
// two kernels (prep Gf = B-fragments of G; main = staged MFMA GEMM).
// Main: 256 blocks x 512 thr (8 waves); wave w = k-group (w&3), d-half (w>>2),
// 8 MFMA steps; X staged bf16 in LDS with 16B-slot XOR swizzle; obs/mask
// global loads issued FIRST (HBM stream starts before L2-resident Gf preload).
// Cross-round evidence: kernel time ~2.8-3.0 us vs 2.8 us HBM floor (17.8 MB);
// remaining ~10 us of dur_us is fixed graph/launch overhead.

#define D_DIM 512
#define K_DIM 64
#define B_DIM 4096

typedef __attribute__((ext_vector_type(4))) float f32x4;
typedef __attribute__((ext_vector_type(8))) short bf16x8;

__device__ __forceinline__ unsigned short f2bf(float f) {
    unsigned u = __builtin_bit_cast(unsigned, f);
    u += 0x7fffu + ((u >> 16) & 1u);          // RNE
    return (unsigned short)(u >> 16);
}

// Gf fragment tensor: Gf[w][tp][lane][j] (bf16), w=wave 0..7, tp=k-step 0..7.
// Element = G[d][n], d = (w>>2)*256 + tp*32 + (lane>>4)*8 + j,
//                    n = (w&3)*16 + (lane&15).
__global__ void prep_Gf_kernel(const float* __restrict__ F,
                               const float* __restrict__ W,
                               unsigned short* __restrict__ Gf) {
    int i = blockIdx.x * blockDim.x + threadIdx.x;  // 0..4095
    int lane = i & 63;
    int tp   = (i >> 6) & 7;
    int w    = i >> 9;
    int n     = (w & 3) * 16 + (lane & 15);
    int dbase = (w >> 2) * 256 + tp * 32 + (lane >> 4) * 8;
    unsigned short v[8];
#pragma unroll
    for (int j = 0; j < 8; ++j) {
        int d = dbase + j;
        float s = 0.f;
#pragma unroll
        for (int f = 0; f < 10; ++f)
            s = fmaf(F[d * 10 + f], W[f * 64 + n], s);
        v[j] = f2bf(s);
    }
    *reinterpret_cast<ushort4*>(Gf + (size_t)i * 8)     = make_ushort4(v[0], v[1], v[2], v[3]);
    *reinterpret_cast<ushort4*>(Gf + (size_t)i * 8 + 4) = make_ushort4(v[4], v[5], v[6], v[7]);
}

// 256 blocks x 512 threads (8 waves). Block = 16 rows x 64 k, full D=512.
// Wave w: n-group (w&3) of 16 k's, d-half (w>>2); 8 MFMA steps of 32 d.
// X staged in LDS bf16 [16][512] with 16B-slot XOR swizzle byte^=((row&7)<<4).
__global__ __launch_bounds__(512, 2)
void main_kernel(const float* __restrict__ obs,
                 const float* __restrict__ mask,
                 const float* __restrict__ bvec,
                 const float* __restrict__ W,
                 const float* __restrict__ bw,
                 const unsigned short* __restrict__ Gf,
                 float* __restrict__ out) {
    __shared__ __align__(16) unsigned short Xs[16 * 512];  // 16 KB
    __shared__ float part[8][64][4];                       // 8 KB
    __shared__ float s0s[16], s1s[16];

    const int tid  = threadIdx.x;
    const int lane = tid & 63;
    const int w    = tid >> 6;
    const int rowbase = blockIdx.x * 16;

    // ---- 1. issue HBM staging loads FIRST (the critical stream) ----
    const int r = tid >> 5;       // row 0..15 (32 threads per row)
    const int c = tid & 31;
    const float* orow = obs  + (size_t)(rowbase + r) * D_DIM;
    const float* mrow = mask + (size_t)(rowbase + r) * D_DIM;
    f32x4 o[4], m[4], bv[4];
#pragma unroll
    for (int j = 0; j < 4; ++j) {
        int d = c * 4 + 128 * j;
        o[j]  = *reinterpret_cast<const f32x4*>(orow + d);
        m[j]  = *reinterpret_cast<const f32x4*>(mrow + d);
        bv[j] = *reinterpret_cast<const f32x4*>(bvec + d);
    }

    // ---- 2. preload this wave's G fragments (L2-resident, 64 KB total) ----
    bf16x8 gfr[8];
#pragma unroll
    for (int tp = 0; tp < 8; ++tp)
        gfr[tp] = *reinterpret_cast<const bf16x8*>(
            Gf + ((size_t)(w * 8 + tp) * 64 + lane) * 8);

    // epilogue constants (per-lane k)
    const int kk = (w & 3) * 16 + (lane & 15);
    const float w10 = W[10 * K_DIM + kk];
    const float bwv = bw[kk];

    // ---- 3. finish stage: X -> LDS bf16 (swizzled), s0/s1 reductions ----
    {
        float p0 = 0.f, p1 = 0.f;
        const int swz = (r & 7) << 4;
        char* xb = reinterpret_cast<char*>(Xs);
#pragma unroll
        for (int j = 0; j < 4; ++j) {
            ushort4 pk;
            pk.x = f2bf(o[j].x * m[j].x);
            pk.y = f2bf(o[j].y * m[j].y);
            pk.z = f2bf(o[j].z * m[j].z);
            pk.w = f2bf(o[j].w * m[j].w);
            int byteoff = r * 1024 + ((c * 8 + 256 * j) ^ swz);
            *reinterpret_cast<ushort4*>(xb + byteoff) = pk;
            p0 += (m[j].x + m[j].y) + (m[j].z + m[j].w);
            p1 = fmaf(m[j].x, bv[j].x, p1);
            p1 = fmaf(m[j].y, bv[j].y, p1);
            p1 = fmaf(m[j].z, bv[j].z, p1);
            p1 = fmaf(m[j].w, bv[j].w, p1);
        }
#pragma unroll
        for (int s = 1; s <= 16; s <<= 1) {   // reduce within 32-lane row-group
            p0 += __shfl_xor(p0, s, 64);
            p1 += __shfl_xor(p1, s, 64);
        }
        if (c == 0) { s0s[r] = p0; s1s[r] = p1; }
    }
    __syncthreads();

    // ---- 4. MFMA: 8 steps of K=32 over this wave's d-half ----
    f32x4 acc = {0.f, 0.f, 0.f, 0.f};
    {
        const int row = lane & 15;
        const int g   = lane >> 4;
        const int swz = (row & 7) << 4;
        const int h   = w >> 2;
        const char* xb = reinterpret_cast<const char*>(Xs);
#pragma unroll
        for (int tp = 0; tp < 8; ++tp) {
            int byteoff = row * 1024 + ((512 * h + 64 * tp + 16 * g) ^ swz);
            bf16x8 a = *reinterpret_cast<const bf16x8*>(xb + byteoff);
            acc = __builtin_amdgcn_mfma_f32_16x16x32_bf16(a, gfr[tp], acc, 0, 0, 0);
        }
    }

    // ---- 5. combine d-halves, epilogue, store ----
#pragma unroll
    for (int rr = 0; rr < 4; ++rr) part[w][lane][rr] = acc[rr];
    __syncthreads();

    if (w < 4) {
        const int g = lane >> 4;
#pragma unroll
        for (int rr = 0; rr < 4; ++rr) {
            const int rowl = g * 4 + rr;             // C/D: row=(lane>>4)*4+reg
            float tot = part[w][lane][rr] + part[w + 4][lane][rr];
            tot = fmaf(s1s[rowl], w10, tot);
            tot = fmaf(s0s[rowl], bwv, tot);
            out[(size_t)(rowbase + rowl) * K_DIM + kk] = fmaxf(tot, 0.f);
        }
    }
}

extern "C" void kernel_launch(void* const* d_in, const int* in_sizes, int n_in,
                              void* d_out, int out_size, void* d_ws, size_t ws_size,
                              hipStream_t stream) {
    const float* obs  = (const float*)d_in[0];  // [4096, 512]
    const float* mask = (const float*)d_in[1];  // [4096, 512]
    const float* F    = (const float*)d_in[2];  // [1, 512, 10]
    const float* bvec = (const float*)d_in[3];  // [1, 512, 1]
    const float* W    = (const float*)d_in[4];  // [11, 64]
    const float* bw   = (const float*)d_in[5];  // [64]
    float* out = (float*)d_out;                 // [4096, 64]
    unsigned short* Gf = (unsigned short*)d_ws; // 32768 bf16 = 64 KB

    prep_Gf_kernel<<<16, 256, 0, stream>>>(F, W, Gf);
    main_kernel<<<B_DIM / 16, 512, 0, stream>>>(obs, mask, bvec, W, bw, Gf, out);
}